// Round 19
// baseline (640.738 us; speedup 1.0000x reference)
//
#include <hip/hip_runtime.h>
#include <math.h>

#define N_NODES 20000
#define N_EDGES 240000

typedef _Float16 half2_t __attribute__((ext_vector_type(2)));
typedef _Float16 f16x8   __attribute__((ext_vector_type(8)));
typedef float    f32x4v  __attribute__((ext_vector_type(4)));
typedef unsigned uint4v  __attribute__((ext_vector_type(4)));

__device__ __forceinline__ float siluf(float v){ return v * (1.0f/(1.0f+__expf(-v))); }
__device__ __forceinline__ float sigmf(float v){ return 1.0f/(1.0f+__expf(-v)); }

__device__ __forceinline__ unsigned pack_h2(float a, float b){
  half2_t h; h.x = (_Float16)a; h.y = (_Float16)b;
  return __builtin_bit_cast(unsigned, h);
}
__device__ __forceinline__ float2 unpack_h2(unsigned u){
  half2_t h = __builtin_bit_cast(half2_t, u);
  return make_float2((float)h.x, (float)h.y);
}
__device__ __forceinline__ float dot2f(unsigned w, unsigned h, float acc){
#if __has_builtin(__builtin_amdgcn_fdot2)
  return __builtin_amdgcn_fdot2(__builtin_bit_cast(half2_t,w),
                                __builtin_bit_cast(half2_t,h), acc, false);
#else
  half2_t a = __builtin_bit_cast(half2_t,w), b = __builtin_bit_cast(half2_t,h);
  return acc + (float)a.x*(float)b.x + (float)a.y*(float)b.y;
#endif
}
__device__ __forceinline__ float dot8q(uint4v w, uint4v h, float acc){
  acc = dot2f(w.x, h.x, acc);
  acc = dot2f(w.y, h.y, acc);
  acc = dot2f(w.z, h.z, acc);
  return dot2f(w.w, h.w, acc);
}

// ---------------------------------------------------------------------------
// CSR build: count -> scan -> scatter
// ---------------------------------------------------------------------------
__global__ void k_count(const int* __restrict__ ei, int* __restrict__ cnt){
  int e = blockIdx.x*blockDim.x + threadIdx.x;
  if (e < N_EDGES) atomicAdd(&cnt[ei[N_EDGES + e]], 1);
}

__global__ void k_scan(const int* __restrict__ cnt, int* __restrict__ off, int* __restrict__ pos){
  __shared__ int part[1024];
  int t = threadIdx.x;
  int c[20]; int s = 0;
  #pragma unroll
  for (int j=0;j<20;j++){
    int idx = t*20 + j;
    int v = (idx < N_NODES) ? cnt[idx] : 0;
    c[j] = s; s += v;
  }
  part[t] = s;
  __syncthreads();
  for (int d=1; d<1024; d<<=1){
    int add = (t>=d) ? part[t-d] : 0;
    __syncthreads();
    part[t] += add;
    __syncthreads();
  }
  int excl = part[t] - s;
  #pragma unroll
  for (int j=0;j<20;j++){
    int idx = t*20 + j;
    if (idx < N_NODES){ off[idx] = excl + c[j]; pos[idx] = excl + c[j]; }
  }
  if (t == 1023) off[N_NODES] = part[1023];
}

__global__ void k_scatter(const int* __restrict__ ei, int* __restrict__ pos,
                          int* __restrict__ perm, int* __restrict__ srcs){
  int e = blockIdx.x*blockDim.x + threadIdx.x;
  if (e >= N_EDGES) return;
  int d = ei[N_EDGES + e];
  int p = atomicAdd(&pos[d], 1);
  perm[e] = p;
  srcs[p] = ei[e];
}

// ---------------------------------------------------------------------------
// Edge geometry in CSR order. Slots 0-2: sh1. Slots 3-7: m1d matrix
// M00,M01,M02,M12,M22 (M11 = -(M00+M22)); exact regroup of CG121.
// Slots 8-23: radial basis.
// ---------------------------------------------------------------------------
__global__ void k_geom(const float* __restrict__ ev, const int* __restrict__ perm,
                       float* __restrict__ eg){
  int e = blockIdx.x*blockDim.x + threadIdx.x;
  if (e >= N_EDGES) return;
  float x = ev[3*e+0], y = ev[3*e+1], z = ev[3*e+2];
  float r = sqrtf(x*x + y*y + z*z);
  float inv = 1.0f / fmaxf(r, 1e-12f);
  float ux = x*inv, uy = y*inv, uz = z*inv;
  float* o = eg + (size_t)perm[e]*24;
  o[0] = 1.7320508f*ux; o[1] = 1.7320508f*uy; o[2] = 1.7320508f*uz;
  float s20 = 3.8729833f*ux*uy;
  float s21 = 3.8729833f*uy*uz;
  float s22 = 1.1180340f*(3.0f*uz*uz - 1.0f);
  float s23 = 3.8729833f*uz*ux;
  float s24 = 1.9364917f*(ux*ux - uy*uy);
  const float c1 = 0.31622777f, c2 = 0.18257419f;
  o[3] = c1*s24 - c2*s22;   // M00
  o[4] = c1*s20;            // M01
  o[5] = c1*s23;            // M02
  o[6] = c1*s21;            // M12
  o[7] = 2.0f*c2*s22;       // M22
  const float invstep = 17.0f/3.15f;
  float t = r*invstep;
  #pragma unroll
  for (int i=0;i<16;i++){
    float d = t - (float)(i+1);
    float a = 1.0f + d, b = 1.0f - d;
    float v = 0.0f;
    if (a > 0.0f && b > 0.0f) v = 33.734292f*__expf(-1.0f/a - 1.0f/b);
    o[8+i] = v;
  }
}

// ---------------------------------------------------------------------------
// Pack node-linear weights as f16 pairs, column-major: WP[col][k/2].
// ---------------------------------------------------------------------------
__global__ void k_packw(const float* __restrict__ Wu,
                        const float* __restrict__ Ws,  const float* __restrict__ Wl,
                        const float* __restrict__ Wlo, const float* __restrict__ Wso,
                        unsigned* __restrict__ WPu,
                        unsigned* __restrict__ WPs,  unsigned* __restrict__ WPl,
                        unsigned* __restrict__ WPlo, unsigned* __restrict__ WPso){
  int i = blockIdx.x*blockDim.x + threadIdx.x;
  const float f12 = 1.0f/12.0f;
  const float is128 = 0.08838835f;
  if (i < 144*72){
    int t = i/72, k2 = i%72;
    WPu[i] = pack_h2(Wu[(2*k2)*144+t]*f12, Wu[(2*k2+1)*144+t]*f12);
  } else if (i < 144*72 + 144*64){
    int ii = i - 144*72; int t = ii/64, k2 = ii%64;
    WPs[ii] = pack_h2(Ws[(2*k2)*144+t]*is128, Ws[(2*k2+1)*144+t]*is128);
  } else if (i < 144*72 + 144*64 + 128*64){
    int ii = i - 144*72 - 144*64; int t = ii/64, k2 = ii%64;
    WPl[ii] = pack_h2(Wl[(2*k2)*128+t]*is128, Wl[(2*k2+1)*128+t]*is128);
  } else if (i < 144*72 + 144*64 + 128*64 + 128*64){
    int ii = i - 144*72 - 144*64 - 128*64; int t = ii/64, k2 = ii%64;
    WPlo[ii] = pack_h2(Wlo[(2*k2)*128+t]*is128, Wlo[(2*k2+1)*128+t]*is128);
  } else if (i < 144*72 + 144*64 + 128*64 + 128*64 + 4*64){
    int ii = i - 144*72 - 144*64 - 128*64 - 128*64; int t = ii/64, k2 = ii%64;
    WPso[ii] = pack_h2(Wso[(2*k2)*4+t]*is128, Wso[(2*k2+1)*4+t]*is128);
  }
}

// ---------------------------------------------------------------------------
// Node L1: X0L1 stored f16 (N x 64)
// ---------------------------------------------------------------------------
__global__ void k_node_l1(const int* __restrict__ xs, const float* __restrict__ emb,
                          const float* __restrict__ Wlin, const float* __restrict__ Wsc,
                          _Float16* __restrict__ X0, float* __restrict__ SC0){
  __shared__ float hs[4][64];
  int n0 = blockIdx.x*4;
  int t  = threadIdx.x;
  {
    int j = t>>6, k = t&63;
    hs[j][k] = emb[xs[n0+j]*64 + k];
  }
  __syncthreads();
  if (t < 64){
    float acc[4] = {};
    for (int k=0;k<64;k++){
      float wv = Wlin[k*64 + t];
      #pragma unroll
      for (int j=0;j<4;j++) acc[j] += hs[j][k]*wv;
    }
    #pragma unroll
    for (int j=0;j<4;j++) X0[(size_t)(n0+j)*64 + t] = (_Float16)(acc[j]*0.125f);
  } else if (t < 208){
    int o = t - 64;
    float acc[4] = {};
    for (int k=0;k<64;k++){
      float wv = Wsc[k*144 + o];
      #pragma unroll
      for (int j=0;j<4;j++) acc[j] += hs[j][k]*wv;
    }
    #pragma unroll
    for (int j=0;j<4;j++) SC0[(size_t)(n0+j)*144 + o] = acc[j]*0.125f;
  }
}

// ---------------------------------------------------------------------------
// Radial hidden for ALL edges: H[e][64] = silu(hb@W1/4), f16.
// ---------------------------------------------------------------------------
__global__ __launch_bounds__(256) void k_hidden(
    const float* __restrict__ EG, const float* __restrict__ W1,
    _Float16* __restrict__ H){
  __shared__ float w1s[16*64];
  int tid = threadIdx.x;
  for (int i=tid;i<16*64;i+=256) w1s[i] = W1[i]*0.25f;
  __syncthreads();
  int lane = tid & 63, wib = tid >> 6;
  int gw = blockIdx.x*4 + wib, nw = gridDim.x*4;
  for (int e = gw; e < N_EDGES; e += nw){
    const float* g8 = EG + (size_t)e*24 + 8;
    float a0 = 0.0f, a1 = 0.0f;
    #pragma unroll
    for (int b=0;b<8;b++){
      a0 = fmaf(g8[b],   w1s[b*64 + lane],     a0);
      a1 = fmaf(g8[8+b], w1s[(8+b)*64 + lane], a1);
    }
    H[(size_t)e*64 + lane] = (_Float16)siluf(a0 + a1);
  }
}

// ---------------------------------------------------------------------------
// Column scale folding
// ---------------------------------------------------------------------------
template<int MODE>
__device__ __forceinline__ float colscale(int c){
  if constexpr (MODE == 1){           // L2
    if (c >= 272 && c < 288) return 0.57735027f;   // m0b 1/sqrt(3)
    if (c >= 288 && c < 304) return 0.40824829f;   // m1c 1/sqrt(6)
    return 1.0f;
  } else if constexpr (MODE == 2){    // LO
    return (c >= 128) ? 0.57735027f : 1.0f;        // m0b 1/sqrt(3)
  }
  return 1.0f;                        // L1
}

// ---------------------------------------------------------------------------
// Pure MFMA GEMM over edge chunk, LINEAR column layout (coalesced store;
// layouts HW-verified R9/R10)
// ---------------------------------------------------------------------------
template<int NT, int MODE>
__global__ __launch_bounds__(256) void k_ww_mfma(
    int e0c, int e1c, const _Float16* __restrict__ H,
    const float* __restrict__ W2, _Float16* __restrict__ WW){
  constexpr int NCOL = NT*16;
  constexpr int NTW  = (NT + 3) / 4;      // col-tiles per wave
  int tid = threadIdx.x;
  int lane = tid & 63, wib = tid >> 6;
  int row = lane & 15, quad = lane >> 4;
  const float fold = 0.125f*0.28867513f;  // 1/8 * 1/sqrt(12)
  f16x8 B0[NTW], B1[NTW];
  #pragma unroll
  for (int t2=0; t2<NTW; t2++){
    int ct = wib*NTW + t2;
    int c  = ct*16 + row;
    bool valid = (ct < NT);
    float fs = valid ? fold*colscale<MODE>(c) : 0.0f;
    int ci = valid ? c : 0;
    #pragma unroll
    for (int j=0;j<8;j++){
      B0[t2][j] = (_Float16)(W2[(quad*8+j)*NCOL + ci]*fs);
      B1[t2][j] = (_Float16)(W2[(32+quad*8+j)*NCOL + ci]*fs);
    }
  }
  int ntiles = (e1c - e0c) >> 4;
  for (int t = blockIdx.x; t < ntiles; t += gridDim.x){
    int eb = e0c + t*16;
    const _Float16* hp = H + (size_t)(eb + row)*64 + quad*8;
    f16x8 A0 = *(const f16x8*)hp;
    f16x8 A1 = *(const f16x8*)(hp + 32);
    #pragma unroll
    for (int t2=0; t2<NTW; t2++){
      int ct = wib*NTW + t2;
      f32x4v d = __builtin_amdgcn_mfma_f32_16x16x32_f16(A0, B0[t2], (f32x4v){0.f,0.f,0.f,0.f}, 0,0,0);
      d = __builtin_amdgcn_mfma_f32_16x16x32_f16(A1, B1[t2], d, 0,0,0);
      if (ct < NT){
        int c0 = ct*16;
        #pragma unroll
        for (int j=0;j<4;j++){
          WW[(size_t)(eb - e0c + quad*4 + j)*NCOL + c0 + row] = (_Float16)d[j];
        }
      }
    }
  }
}

// ---------------------------------------------------------------------------
// L1 gather: linear WW, f16 X0 (src-prefetch)
// ---------------------------------------------------------------------------
__global__ __launch_bounds__(256) void k_gather_l1(
    const int* __restrict__ off, const int* __restrict__ srcs, const float* __restrict__ eg,
    const _Float16* __restrict__ WW, const _Float16* __restrict__ X0,
    float* __restrict__ A0, float* __restrict__ A1, int e0, int e1, int first){
  int tid = threadIdx.x, lane = tid & 63;
  int gw = (blockIdx.x*256 + tid) >> 6;
  int nw = (gridDim.x*256) >> 6;
  for (int n = gw; n < N_NODES; n += nw){
    int ib = off[n], ie = off[n+1];
    if (ib < e0) ib = e0;
    if (ie > e1) ie = e1;
    if (!first && ib >= ie) continue;
    float a0a = 0.0f, a1a[3] = {0,0,0};
    if (ib < ie){
      int src = srcs[ib];
      for (int i = ib; i < ie; i++){
        float x0 = (float)X0[(size_t)src*64 + lane];
        if (i+1 < ie) src = srcs[i+1];
        const float* g = eg + (size_t)i*24;
        const _Float16* w = WW + (size_t)(i - e0)*128;
        float w0  = (float)w[lane];
        float w1v = (float)w[64 + lane];
        float m0 = x0*w0, m1 = x0*w1v;
        a0a += m0;
        a1a[0] += m1*g[0]; a1a[1] += m1*g[1]; a1a[2] += m1*g[2];
      }
    }
    float* p = A1 + (size_t)n*192 + lane*3;
    if (first){
      A0[(size_t)n*64 + lane] = a0a;
      p[0] = a1a[0]; p[1] = a1a[1]; p[2] = a1a[2];
    } else {
      A0[(size_t)n*64 + lane] += a0a;
      p[0] += a1a[0]; p[1] += a1a[1]; p[2] += a1a[2];
    }
  }
}

// ---------------------------------------------------------------------------
// L2 gather: linear WW, paired X0, stride-4 X1, precomputed M for m1d
// ---------------------------------------------------------------------------
__global__ __launch_bounds__(256) void k_gather_l2(
    const int* __restrict__ off, const int* __restrict__ srcs, const float* __restrict__ eg,
    const _Float16* __restrict__ WW, const _Float16* __restrict__ X0, const _Float16* __restrict__ X1,
    float* __restrict__ A0, float* __restrict__ A1, int e0, int e1, int first){
  int tid = threadIdx.x, lane = tid & 63;
  int grp = lane >> 4, v = lane & 15;
  int gw = (blockIdx.x*256 + tid) >> 6;
  int nw = (gridDim.x*256) >> 6;
  for (int n = gw; n < N_NODES; n += nw){
    int ib = off[n], ie = off[n+1];
    if (ib < e0) ib = e0;
    if (ie > e1) ie = e1;
    if (!first && ib >= ie) continue;
    float a0a=0.f, a0b=0.f, a0c=0.f;
    float a1a[3]={0,0,0}, a1b[3]={0,0,0}, a1g[3]={0,0,0};
    if (ib < ie){
      int src = srcs[ib];
      for (int i = ib; i < ie; i++){
        float2 x0p = unpack_h2(((const unsigned*)(X0 + (size_t)src*128))[lane]);
        uint2 x1u = ((const uint2*)(X1 + (size_t)src*64))[v];
        float2 xab = unpack_h2(x1u.x);
        float2 xcp = unpack_h2(x1u.y);
        float xx = xab.x, xy = xab.y, xz = xcp.x;
        if (i+1 < ie) src = srcs[i+1];
        const float* g = eg + (size_t)i*24;
        const _Float16* w = WW + (size_t)(i - e0)*320;
        float w0  = (float)w[lane];
        float w1v = (float)w[ 64 + lane];
        float w2v = (float)w[128 + lane];
        float w3v = (float)w[192 + lane];
        float w4  = (float)w[256 + lane];
        float sx = g[0], sy = g[1], sz = g[2];
        a0a += x0p.x*w0;
        a0b += x0p.y*w1v;
        float ma = x0p.x*w2v, mb = x0p.y*w3v;
        a1a[0] += ma*sx; a1a[1] += ma*sy; a1a[2] += ma*sz;
        a1b[0] += mb*sx; a1b[1] += mb*sy; a1b[2] += mb*sz;
        if (grp == 0){
          a1g[0] += w4*xx; a1g[1] += w4*xy; a1g[2] += w4*xz;
        } else if (grp == 1){
          a0c += w4*(xx*sx + xy*sy + xz*sz);
        } else if (grp == 2){
          a1g[0] += w4*(xy*sz - xz*sy);
          a1g[1] += w4*(xz*sx - xx*sz);
          a1g[2] += w4*(xx*sy - xy*sx);
        } else {
          float M00=g[3], M01=g[4], M02=g[5], M12=g[6], M22=g[7];
          float M11 = -(M00 + M22);
          a1g[0] += w4*(xx*M00 + xy*M01 + xz*M02);
          a1g[1] += w4*(xx*M01 + xy*M11 + xz*M12);
          a1g[2] += w4*(xx*M02 + xy*M12 + xz*M22);
        }
      }
    }
    float* a0 = A0 + (size_t)n*144;
    float* a1 = A1 + (size_t)n*528;
    int gbase = (grp == 0) ? 128 : (grp == 2) ? 144 : (grp == 3) ? 160 : -1;
    if (first){
      a0[lane] = a0a;
      a0[64 + lane] = a0b;
      if (grp == 1) a0[128 + v] = a0c;
      float* p = a1 + lane*3;
      p[0] = a1a[0]; p[1] = a1a[1]; p[2] = a1a[2];
      p = a1 + (64 + lane)*3;
      p[0] = a1b[0]; p[1] = a1b[1]; p[2] = a1b[2];
      if (gbase >= 0){
        p = a1 + (gbase + v)*3;
        p[0] = a1g[0]; p[1] = a1g[1]; p[2] = a1g[2];
      }
    } else {
      a0[lane] += a0a;
      a0[64 + lane] += a0b;
      if (grp == 1) a0[128 + v] += a0c;
      float* p = a1 + lane*3;
      p[0] += a1a[0]; p[1] += a1a[1]; p[2] += a1a[2];
      p = a1 + (64 + lane)*3;
      p[0] += a1b[0]; p[1] += a1b[1]; p[2] += a1b[2];
      if (gbase >= 0){
        p = a1 + (gbase + v)*3;
        p[0] += a1g[0]; p[1] += a1g[1]; p[2] += a1g[2];
      }
    }
  }
}

// ---------------------------------------------------------------------------
// LO gather: linear WW, paired X0, stride-4 X1
// ---------------------------------------------------------------------------
__global__ __launch_bounds__(256) void k_gather_lo(
    const int* __restrict__ off, const int* __restrict__ srcs, const float* __restrict__ eg,
    const _Float16* __restrict__ WW, const _Float16* __restrict__ X0, const _Float16* __restrict__ X1,
    float* __restrict__ A0, int e0, int e1, int first){
  int tid = threadIdx.x, lane = tid & 63, v = lane & 15;
  int gw = (blockIdx.x*256 + tid) >> 6;
  int nw = (gridDim.x*256) >> 6;
  for (int n = gw; n < N_NODES; n += nw){
    int ib = off[n], ie = off[n+1];
    if (ib < e0) ib = e0;
    if (ie > e1) ie = e1;
    if (!first && ib >= ie) continue;
    float a0a = 0.f, a0b = 0.f, a0c = 0.f;
    if (ib < ie){
      int src = srcs[ib];
      for (int i = ib; i < ie; i++){
        float2 x0p = unpack_h2(((const unsigned*)(X0 + (size_t)src*128))[lane]);
        uint2 x1u = ((const uint2*)(X1 + (size_t)src*64))[v];
        float2 xab = unpack_h2(x1u.x);
        float2 xcp = unpack_h2(x1u.y);
        if (i+1 < ie) src = srcs[i+1];
        const float* g = eg + (size_t)i*24;
        const _Float16* w = WW + (size_t)(i - e0)*144;
        float w0  = (float)w[lane];
        float w1v = (float)w[64 + lane];
        float w2v = (float)w[128 + v];
        a0a += x0p.x*w0;
        a0b += x0p.y*w1v;
        float dot = xab.x*g[0] + xab.y*g[1] + xcp.x*g[2];
        a0c += w2v*dot;
      }
    }
    float* a0 = A0 + (size_t)n*144;
    if (first){
      a0[lane] = a0a;
      a0[64 + lane] = a0b;
      if (lane < 16) a0[128 + lane] = a0c;
    } else {
      a0[lane] += a0a;
      a0[64 + lane] += a0b;
      if (lane < 16) a0[128 + lane] += a0c;
    }
  }
}

// ---------------------------------------------------------------------------
// L1 update: f32 LDS-staged activations + W21 staged in LDS
// ---------------------------------------------------------------------------
__global__ __launch_bounds__(256) void k_upd_l1(
    const float* __restrict__ A0, const float* __restrict__ A1,
    const float* __restrict__ SC0,
    const float* __restrict__ W20, const float* __restrict__ W21,
    float* __restrict__ H0, float* __restrict__ H1){
  __shared__ float a0s[8*64];
  __shared__ float a1s[8*192];
  __shared__ float w21s[64*16];
  __shared__ float sig[8][16];
  __shared__ float g1s[8][48];
  int n0 = blockIdx.x*8, t = threadIdx.x;
  {
    const float4* s0 = (const float4*)(A0 + (size_t)n0*64);
    float4* d0 = (float4*)a0s;
    for (int i=t;i<8*64/4;i+=256) d0[i] = s0[i];
    const float4* s1 = (const float4*)(A1 + (size_t)n0*192);
    float4* d1 = (float4*)a1s;
    for (int i=t;i<8*192/4;i+=256) d1[i] = s1[i];
    const float4* sw = (const float4*)W21;
    float4* dw = (float4*)w21s;
    for (int i=t;i<64*16/4;i+=256) dw[i] = sw[i];
  }
  __syncthreads();
  if (t < 144){
    float acc[8] = {};
    for (int k=0;k<64;k++){
      float wv = W20[k*144 + t];
      #pragma unroll
      for (int j=0;j<8;j++) acc[j] += a0s[j*64 + k]*wv;
    }
    #pragma unroll
    for (int j=0;j<8;j++){
      float gg = acc[j]*0.125f + SC0[(size_t)(n0+j)*144 + t];
      if (t < 128) H0[(size_t)(n0+j)*128 + t] = siluf(gg);
      else         sig[j][t-128] = sigmf(gg);
    }
  } else if (t < 192){
    int idx = t-144, v = idx/3, k = idx%3;
    float acc[8] = {};
    for (int u=0;u<64;u++){
      float wv = w21s[u*16 + v];
      #pragma unroll
      for (int j=0;j<8;j++) acc[j] += a1s[j*192 + u*3 + k]*wv;
    }
    #pragma unroll
    for (int j=0;j<8;j++) g1s[j][idx] = acc[j]*0.125f;
  }
  __syncthreads();
  if (t >= 144 && t < 192){
    int idx = t-144, v = idx/3;
    #pragma unroll
    for (int j=0;j<8;j++) H1[(size_t)(n0+j)*48 + idx] = sig[j][v]*g1s[j][idx];
  }
}

// ---------------------------------------------------------------------------
// L2 node linears: f16 staging + packed weights; X0 paired, X1 stride-4
// ---------------------------------------------------------------------------
__global__ __launch_bounds__(384) void k_lin_l2(
    const float* __restrict__ H0, const float* __restrict__ H1,
    const unsigned* __restrict__ WPs, const float* __restrict__ Wsc1,
    const unsigned* __restrict__ WPl, const float* __restrict__ Wl1,
    float* __restrict__ SC0, float* __restrict__ SC1,
    _Float16* __restrict__ X0,  _Float16* __restrict__ X1){
  __shared__ uint4v h0h8[128];
  __shared__ float h1s[8*48];
  int n0 = blockIdx.x*8, t = threadIdx.x;
  if (t < 128){
    const float4* s0 = (const float4*)(H0 + (size_t)n0*128);
    float4 f0 = s0[t*2], f1 = s0[t*2+1];
    uint4v u;
    u.x = pack_h2(f0.x, f0.y); u.y = pack_h2(f0.z, f0.w);
    u.z = pack_h2(f1.x, f1.y); u.w = pack_h2(f1.z, f1.w);
    h0h8[t] = u;
  } else if (t < 224){
    int i = t - 128;
    const float4* s1 = (const float4*)(H1 + (size_t)n0*48);
    if (i < 96) ((float4*)h1s)[i] = s1[i];
  }
  __syncthreads();
  const uint4v* wps4 = (const uint4v*)WPs;
  const uint4v* wpl4 = (const uint4v*)WPl;
  if (t < 144){
    float acc[8] = {};
    for (int kq=0;kq<16;kq++){
      uint4v wq = wps4[t*16 + kq];
      #pragma unroll
      for (int j=0;j<8;j++){
        uint4v av = h0h8[j*16 + kq];
        acc[j] = dot8q(wq, av, acc[j]);
      }
    }
    #pragma unroll
    for (int j=0;j<8;j++) SC0[(size_t)(n0+j)*144 + t] = acc[j];
  } else if (t < 192){
    int idx = t-144, v = idx/3, k = idx%3;
    float acc[8] = {};
    for (int u=0;u<16;u++){
      float wv = Wsc1[u*16 + v];
      #pragma unroll
      for (int j=0;j<8;j++) acc[j] += h1s[j*48 + u*3 + k]*wv;
    }
    #pragma unroll
    for (int j=0;j<8;j++) SC1[(size_t)(n0+j)*48 + idx] = acc[j]*0.25f;
  } else if (t < 320){
    int o = t-192;
    float acc[8] = {};
    for (int kq=0;kq<16;kq++){
      uint4v wq = wpl4[o*16 + kq];
      #pragma unroll
      for (int j=0;j<8;j++){
        uint4v av = h0h8[j*16 + kq];
        acc[j] = dot8q(wq, av, acc[j]);
      }
    }
    #pragma unroll
    for (int j=0;j<8;j++) X0[(size_t)(n0+j)*128 + (o&63)*2 + (o>>6)] = (_Float16)acc[j];
  } else if (t < 368){
    int idx = t-320, v = idx/3, k = idx%3;
    float acc[8] = {};
    for (int u=0;u<16;u++){
      float wv = Wl1[u*16 + v];
      #pragma unroll
      for (int j=0;j<8;j++) acc[j] += h1s[j*48 + u*3 + k]*wv;
    }
    #pragma unroll
    for (int j=0;j<8;j++) X1[(size_t)(n0+j)*64 + v*4 + k] = (_Float16)(acc[j]*0.25f);
  }
}

// ---------------------------------------------------------------------------
// L2 update: f16 A0 staging + packed f16 W20 + dot2 + W21 staged in LDS
// ---------------------------------------------------------------------------
__global__ __launch_bounds__(256) void k_upd_l2(
    const float* __restrict__ A0, const float* __restrict__ A1,
    const float* __restrict__ SC0, const float* __restrict__ SC1,
    const unsigned* __restrict__ WPu, const float* __restrict__ W21,
    float* __restrict__ H0, float* __restrict__ H1){
  __shared__ uint4v a0h8[144];
  __shared__ float a1s[8*528];
  __shared__ float w21s[176*16];
  __shared__ float sig[8][16];
  __shared__ float g1s[8][48];
  int n0 = blockIdx.x*8, t = threadIdx.x;
  if (t < 144){
    const float4* s0 = (const float4*)(A0 + (size_t)n0*144);
    float4 f0 = s0[t*2], f1 = s0[t*2+1];
    uint4v u;
    u.x = pack_h2(f0.x, f0.y); u.y = pack_h2(f0.z, f0.w);
    u.z = pack_h2(f1.x, f1.y); u.w = pack_h2(f1.z, f1.w);
    a0h8[t] = u;
  }
  {
    const float4* s1 = (const float4*)(A1 + (size_t)n0*528);
    float4* d1 = (float4*)a1s;
    for (int i=t;i<8*528/4;i+=256) d1[i] = s1[i];
    const float4* sw = (const float4*)W21;
    float4* dw = (float4*)w21s;
    for (int i=t;i<176*16/4;i+=256) dw[i] = sw[i];
  }
  __syncthreads();
  const uint4v* wpu4 = (const uint4v*)WPu;
  if (t < 144){
    float acc[8] = {};
    for (int kq=0;kq<18;kq++){
      uint4v wq = wpu4[t*18 + kq];
      #pragma unroll
      for (int j=0;j<8;j++){
        uint4v av = a0h8[j*18 + kq];
        acc[j] = dot8q(wq, av, acc[j]);
      }
    }
    #pragma unroll
    for (int j=0;j<8;j++){
      float gg = acc[j] + SC0[(size_t)(n0+j)*144 + t];
      if (t < 128) H0[(size_t)(n0+j)*128 + t] = siluf(gg);
      else         sig[j][t-128] = sigmf(gg);
    }
  } else if (t < 192){
    int idx = t-144, v = idx/3, k = idx%3;
    float acc[8] = {};
    for (int u=0;u<176;u++){
      float wv = w21s[u*16 + v];
      #pragma unroll
      for (int j=0;j<8;j++) acc[j] += a1s[j*528 + u*3 + k]*wv;
    }
    #pragma unroll
    for (int j=0;j<8;j++) g1s[j][idx] = acc[j]*0.075377836f + SC1[(size_t)(n0+j)*48 + idx];
  }
  __syncthreads();
  if (t >= 144 && t < 192){
    int idx = t-144, v = idx/3;
    #pragma unroll
    for (int j=0;j<8;j++) H1[(size_t)(n0+j)*48 + idx] = sig[j][v]*g1s[j][idx];
  }
}

// ---------------------------------------------------------------------------
// LO node linears: f16 staging + packed weights; X0 paired, X1 stride-4
// ---------------------------------------------------------------------------
__global__ __launch_bounds__(256) void k_lin_lo(
    const float* __restrict__ H0, const float* __restrict__ H1,
    const unsigned* __restrict__ WPso,
    const unsigned* __restrict__ WPlo, const float* __restrict__ Wl1,
    float* __restrict__ SCO, _Float16* __restrict__ X0, _Float16* __restrict__ X1){
  __shared__ uint4v h0h8[128];
  __shared__ float h1s[8*48];
  int n0 = blockIdx.x*8, t = threadIdx.x;
  if (t < 128){
    const float4* s0 = (const float4*)(H0 + (size_t)n0*128);
    float4 f0 = s0[t*2], f1 = s0[t*2+1];
    uint4v u;
    u.x = pack_h2(f0.x, f0.y); u.y = pack_h2(f0.z, f0.w);
    u.z = pack_h2(f1.x, f1.y); u.w = pack_h2(f1.z, f1.w);
    h0h8[t] = u;
  } else if (t < 224){
    int i = t - 128;
    const float4* s1 = (const float4*)(H1 + (size_t)n0*48);
    if (i < 96) ((float4*)h1s)[i] = s1[i];
  }
  __syncthreads();
  const uint4v* wso4 = (const uint4v*)WPso;
  const uint4v* wlo4 = (const uint4v*)WPlo;
  if (t < 4){
    float acc[8] = {};
    for (int kq=0;kq<16;kq++){
      uint4v wq = wso4[t*16 + kq];
      #pragma unroll
      for (int j=0;j<8;j++){
        uint4v av = h0h8[j*16 + kq];
        acc[j] = dot8q(wq, av, acc[j]);
      }
    }
    #pragma unroll
    for (int j=0;j<8;j++) SCO[(size_t)(n0+j)*4 + t] = acc[j];
  } else if (t < 132){
    int o = t-4;
    float acc[8] = {};
    for (int kq=0;kq<16;kq++){
      uint4v wq = wlo4[o*16 + kq];
      #pragma unroll
      for (int j=0;j<8;j++){
        uint4v av = h0h8[j*16 + kq];
        acc[j] = dot8q(wq, av, acc[j]);
      }
    }
    #pragma unroll
    for (int j=0;j<8;j++) X0[(size_t)(n0+j)*128 + (o&63)*2 + (o>>6)] = (_Float16)acc[j];
  } else if (t < 180){
    int idx = t-132, v = idx/3, k = idx%3;
    float acc[8] = {};
    for (int u=0;u<16;u++){
      float wv = Wl1[u*16 + v];
      #pragma unroll
      for (int j=0;j<8;j++) acc[j] += h1s[j*48 + u*3 + k]*wv;
    }
    #pragma unroll
    for (int j=0;j<8;j++) X1[(size_t)(n0+j)*64 + v*4 + k] = (_Float16)(acc[j]*0.25f);
  }
}

// ---------------------------------------------------------------------------
// Final: out = A0@LO_lin2_0/12 + SCO, 32 nodes/block, 128 active lanes
// ---------------------------------------------------------------------------
__global__ __launch_bounds__(256) void k_final(
    const float* __restrict__ A0, const float* __restrict__ SCO,
    const float* __restrict__ W, float* __restrict__ out){
  __shared__ float a0s[32*144];
  int n0 = blockIdx.x*32, t = threadIdx.x;
  {
    const float4* s0 = (const float4*)(A0 + (size_t)n0*144);
    float4* d0 = (float4*)a0s;
    for (int i=t;i<32*144/4;i+=256) d0[i] = s0[i];
  }
  __syncthreads();
  if (t < 128){
    int j = t >> 2, c = t & 3;
    float acc = 0.0f;
    for (int k=0;k<144;k++) acc += a0s[j*144 + k]*W[k*4 + c];
    int i = (n0 + j)*4 + c;
    out[i] = acc*(1.0f/12.0f) + SCO[i];
  }
}

// ---------------------------------------------------------------------------
extern "C" void kernel_launch(void* const* d_in, const int* in_sizes, int n_in,
                              void* d_out, int out_size, void* d_ws, size_t ws_size,
                              hipStream_t stream) {
  const int*   x   = (const int*)  d_in[0];
  const int*   ei  = (const int*)  d_in[1];
  const float* ev  = (const float*)d_in[2];
  const float* emb = (const float*)d_in[3];
  const float* L1_lin1_0 = (const float*)d_in[4];
  const float* L1_W1     = (const float*)d_in[5];
  const float* L1_W2     = (const float*)d_in[6];
  const float* L1_lin2_0 = (const float*)d_in[7];
  const float* L1_lin2_1 = (const float*)d_in[8];
  const float* L1_sc_0   = (const float*)d_in[9];
  const float* L2_lin1_0 = (const float*)d_in[10];
  const float* L2_lin1_1 = (const float*)d_in[11];
  const float* L2_W1     = (const float*)d_in[12];
  const float* L2_W2     = (const float*)d_in[13];
  const float* L2_lin2_0 = (const float*)d_in[14];
  const float* L2_lin2_1 = (const float*)d_in[15];
  const float* L2_sc_0   = (const float*)d_in[16];
  const float* L2_sc_1   = (const float*)d_in[17];
  const float* LO_lin1_0 = (const float*)d_in[18];
  const float* LO_lin1_1 = (const float*)d_in[19];
  const float* LO_W1     = (const float*)d_in[20];
  const float* LO_W2     = (const float*)d_in[21];
  const float* LO_lin2_0 = (const float*)d_in[22];
  const float* LO_sc_0   = (const float*)d_in[23];
  float* out = (float*)d_out;

  int* cnt  = (int*)d_ws;                    // N
  int* off  = cnt  + N_NODES;                // N+1
  int* pos  = off  + N_NODES + 1;            // N
  int* perm = pos  + N_NODES;                // E
  int* srcs = perm + N_EDGES;                // E  (pad ints to 540004 for 16B alignment)
  float* EG  = (float*)(((char*)d_ws) + ((size_t)540004 * 4));   // E*24
  _Float16* X0 = (_Float16*)(EG + (size_t)N_EDGES*24);  // N*128 f16 (paired; L1 uses first N*64)
  _Float16* X1 = (_Float16*)(X0 + (size_t)N_NODES*128); // N*64 f16 (stride-4)
  float* SC0 = (float*)(X1 + (size_t)N_NODES*64);       // N*144
  float* SC1 = SC0 + (size_t)N_NODES*144;    // N*48
  float* A0  = SC1 + (size_t)N_NODES*48;     // N*144
  float* A1  = A0  + (size_t)N_NODES*144;    // N*528
  float* H0  = A1  + (size_t)N_NODES*528;    // N*128
  float* H1  = H0  + (size_t)N_NODES*128;    // N*48
  _Float16* HH = (_Float16*)(H1 + (size_t)N_NODES*48);  // E*64 f16
  unsigned* WPu  = (unsigned*)(HH + (size_t)N_EDGES*64); // 144*72
  unsigned* WPs  = WPu  + 144*72;                        // 144*64
  unsigned* WPl  = WPs  + 144*64;                        // 128*64
  unsigned* WPlo = WPl  + 128*64;                        // 128*64
  unsigned* WPso = WPlo + 128*64;                        // 4*64
  _Float16* WW = (_Float16*)(WPso + 4*64);               // dynamic

  size_t used = (size_t)((char*)WW - (char*)d_ws);
  size_t avail = (ws_size > used) ? (ws_size - used) : 0;
  auto chunk_for = [&](int ncol)->int{
    size_t ce = avail / ((size_t)ncol * sizeof(_Float16));
    if (ce >= (size_t)N_EDGES) return N_EDGES;
    int c = (int)ce & ~15;
    return c < 4096 ? 4096 : c;
  };

  // CSR build + weight packing
  hipMemsetAsync(cnt, 0, N_NODES*sizeof(int), stream);
  k_count  <<<(N_EDGES+255)/256, 256, 0, stream>>>(ei, cnt);
  k_scan   <<<1, 1024, 0, stream>>>(cnt, off, pos);
  k_scatter<<<(N_EDGES+255)/256, 256, 0, stream>>>(ei, pos, perm, srcs);
  k_geom   <<<(N_EDGES+255)/256, 256, 0, stream>>>(ev, perm, EG);
  k_packw  <<<142, 256, 0, stream>>>(L2_lin2_0, L2_sc_0, L2_lin1_0,
                                     LO_lin1_0, LO_sc_0,
                                     WPu, WPs, WPl, WPlo, WPso);

  // ---- L1 ----
  k_node_l1<<<N_NODES/4, 256, 0, stream>>>(x, emb, L1_lin1_0, L1_sc_0, X0, SC0);
  k_hidden<<<2048, 256, 0, stream>>>(EG, L1_W1, HH);
  {
    int chunk = chunk_for(128);
    for (int e0 = 0; e0 < N_EDGES; e0 += chunk){
      int e1 = (e0 + chunk < N_EDGES) ? e0 + chunk : N_EDGES;
      k_ww_mfma<8,0><<<2048, 256, 0, stream>>>(e0, e1, HH, L1_W2, WW);
      k_gather_l1<<<5000, 256, 0, stream>>>(off, srcs, EG, WW, X0, A0, A1, e0, e1, e0==0);
    }
  }
  k_upd_l1<<<N_NODES/8, 256, 0, stream>>>(A0, A1, SC0, L1_lin2_0, L1_lin2_1, H0, H1);

  // ---- L2 ----
  k_lin_l2<<<N_NODES/8, 384, 0, stream>>>(H0, H1, WPs, L2_sc_1, WPl, L2_lin1_1,
                                          SC0, SC1, X0, X1);
  k_hidden<<<2048, 256, 0, stream>>>(EG, L2_W1, HH);
  {
    int chunk = chunk_for(320);
    for (int e0 = 0; e0 < N_EDGES; e0 += chunk){
      int e1 = (e0 + chunk < N_EDGES) ? e0 + chunk : N_EDGES;
      k_ww_mfma<20,1><<<2048, 256, 0, stream>>>(e0, e1, HH, L2_W2, WW);
      k_gather_l2<<<5000, 256, 0, stream>>>(off, srcs, EG, WW, X0, X1, A0, A1, e0, e1, e0==0);
    }
  }
  k_upd_l2<<<N_NODES/8, 256, 0, stream>>>(A0, A1, SC0, SC1, WPu, L2_lin2_1, H0, H1);

  // ---- LO ----
  k_lin_lo<<<N_NODES/8, 256, 0, stream>>>(H0, H1, WPso, WPlo, LO_lin1_1, SC1, X0, X1);
  k_hidden<<<2048, 256, 0, stream>>>(EG, LO_W1, HH);
  {
    int chunk = chunk_for(144);
    for (int e0 = 0; e0 < N_EDGES; e0 += chunk){
      int e1 = (e0 + chunk < N_EDGES) ? e0 + chunk : N_EDGES;
      k_ww_mfma<9,2><<<2048, 256, 0, stream>>>(e0, e1, HH, LO_W2, WW);
      k_gather_lo<<<5000, 256, 0, stream>>>(off, srcs, EG, WW, X0, X1, A0, e0, e1, e0==0);
    }
  }
  k_final<<<N_NODES/32, 256, 0, stream>>>(A0, SC1, LO_lin2_0, out);
}

// Round 20
// 618.782 us; speedup vs baseline: 1.0355x; 1.0355x over previous
//
#include <hip/hip_runtime.h>
#include <math.h>

#define N_NODES 20000
#define N_EDGES 240000

typedef _Float16 half2_t __attribute__((ext_vector_type(2)));
typedef _Float16 f16x8   __attribute__((ext_vector_type(8)));
typedef float    f32x4v  __attribute__((ext_vector_type(4)));
typedef unsigned uint4v  __attribute__((ext_vector_type(4)));

__device__ __forceinline__ float siluf(float v){ return v * (1.0f/(1.0f+__expf(-v))); }
__device__ __forceinline__ float sigmf(float v){ return 1.0f/(1.0f+__expf(-v)); }

__device__ __forceinline__ unsigned pack_h2(float a, float b){
  half2_t h; h.x = (_Float16)a; h.y = (_Float16)b;
  return __builtin_bit_cast(unsigned, h);
}
__device__ __forceinline__ float2 unpack_h2(unsigned u){
  half2_t h = __builtin_bit_cast(half2_t, u);
  return make_float2((float)h.x, (float)h.y);
}
__device__ __forceinline__ float dot2f(unsigned w, unsigned h, float acc){
#if __has_builtin(__builtin_amdgcn_fdot2)
  return __builtin_amdgcn_fdot2(__builtin_bit_cast(half2_t,w),
                                __builtin_bit_cast(half2_t,h), acc, false);
#else
  half2_t a = __builtin_bit_cast(half2_t,w), b = __builtin_bit_cast(half2_t,h);
  return acc + (float)a.x*(float)b.x + (float)a.y*(float)b.y;
#endif
}
__device__ __forceinline__ float dot8q(uint4v w, uint4v h, float acc){
  acc = dot2f(w.x, h.x, acc);
  acc = dot2f(w.y, h.y, acc);
  acc = dot2f(w.z, h.z, acc);
  return dot2f(w.w, h.w, acc);
}

// ---------------------------------------------------------------------------
// CSR build: count -> scan -> scatter
// ---------------------------------------------------------------------------
__global__ void k_count(const int* __restrict__ ei, int* __restrict__ cnt){
  int e = blockIdx.x*blockDim.x + threadIdx.x;
  if (e < N_EDGES) atomicAdd(&cnt[ei[N_EDGES + e]], 1);
}

__global__ void k_scan(const int* __restrict__ cnt, int* __restrict__ off, int* __restrict__ pos){
  __shared__ int part[1024];
  int t = threadIdx.x;
  int c[20]; int s = 0;
  #pragma unroll
  for (int j=0;j<20;j++){
    int idx = t*20 + j;
    int v = (idx < N_NODES) ? cnt[idx] : 0;
    c[j] = s; s += v;
  }
  part[t] = s;
  __syncthreads();
  for (int d=1; d<1024; d<<=1){
    int add = (t>=d) ? part[t-d] : 0;
    __syncthreads();
    part[t] += add;
    __syncthreads();
  }
  int excl = part[t] - s;
  #pragma unroll
  for (int j=0;j<20;j++){
    int idx = t*20 + j;
    if (idx < N_NODES){ off[idx] = excl + c[j]; pos[idx] = excl + c[j]; }
  }
  if (t == 1023) off[N_NODES] = part[1023];
}

__global__ void k_scatter(const int* __restrict__ ei, int* __restrict__ pos,
                          int* __restrict__ perm, int* __restrict__ srcs){
  int e = blockIdx.x*blockDim.x + threadIdx.x;
  if (e >= N_EDGES) return;
  int d = ei[N_EDGES + e];
  int p = atomicAdd(&pos[d], 1);
  perm[e] = p;
  srcs[p] = ei[e];
}

// ---------------------------------------------------------------------------
// Edge geometry in CSR order. Slots 0-2: sh1. Slots 3-7: m1d matrix
// M00,M01,M02,M12,M22 (M11 = -(M00+M22)); exact regroup of CG121.
// Slots 8-23: radial basis.
// ---------------------------------------------------------------------------
__global__ void k_geom(const float* __restrict__ ev, const int* __restrict__ perm,
                       float* __restrict__ eg){
  int e = blockIdx.x*blockDim.x + threadIdx.x;
  if (e >= N_EDGES) return;
  float x = ev[3*e+0], y = ev[3*e+1], z = ev[3*e+2];
  float r = sqrtf(x*x + y*y + z*z);
  float inv = 1.0f / fmaxf(r, 1e-12f);
  float ux = x*inv, uy = y*inv, uz = z*inv;
  float* o = eg + (size_t)perm[e]*24;
  o[0] = 1.7320508f*ux; o[1] = 1.7320508f*uy; o[2] = 1.7320508f*uz;
  float s20 = 3.8729833f*ux*uy;
  float s21 = 3.8729833f*uy*uz;
  float s22 = 1.1180340f*(3.0f*uz*uz - 1.0f);
  float s23 = 3.8729833f*uz*ux;
  float s24 = 1.9364917f*(ux*ux - uy*uy);
  const float c1 = 0.31622777f, c2 = 0.18257419f;
  o[3] = c1*s24 - c2*s22;   // M00
  o[4] = c1*s20;            // M01
  o[5] = c1*s23;            // M02
  o[6] = c1*s21;            // M12
  o[7] = 2.0f*c2*s22;       // M22
  const float invstep = 17.0f/3.15f;
  float t = r*invstep;
  #pragma unroll
  for (int i=0;i<16;i++){
    float d = t - (float)(i+1);
    float a = 1.0f + d, b = 1.0f - d;
    float v = 0.0f;
    if (a > 0.0f && b > 0.0f) v = 33.734292f*__expf(-1.0f/a - 1.0f/b);
    o[8+i] = v;
  }
}

// ---------------------------------------------------------------------------
// Pack node-linear weights as f16 pairs, column-major: WP[col][k/2].
// ---------------------------------------------------------------------------
__global__ void k_packw(const float* __restrict__ Wu,
                        const float* __restrict__ Ws,  const float* __restrict__ Wl,
                        const float* __restrict__ Wlo, const float* __restrict__ Wso,
                        unsigned* __restrict__ WPu,
                        unsigned* __restrict__ WPs,  unsigned* __restrict__ WPl,
                        unsigned* __restrict__ WPlo, unsigned* __restrict__ WPso){
  int i = blockIdx.x*blockDim.x + threadIdx.x;
  const float f12 = 1.0f/12.0f;
  const float is128 = 0.08838835f;
  if (i < 144*72){
    int t = i/72, k2 = i%72;
    WPu[i] = pack_h2(Wu[(2*k2)*144+t]*f12, Wu[(2*k2+1)*144+t]*f12);
  } else if (i < 144*72 + 144*64){
    int ii = i - 144*72; int t = ii/64, k2 = ii%64;
    WPs[ii] = pack_h2(Ws[(2*k2)*144+t]*is128, Ws[(2*k2+1)*144+t]*is128);
  } else if (i < 144*72 + 144*64 + 128*64){
    int ii = i - 144*72 - 144*64; int t = ii/64, k2 = ii%64;
    WPl[ii] = pack_h2(Wl[(2*k2)*128+t]*is128, Wl[(2*k2+1)*128+t]*is128);
  } else if (i < 144*72 + 144*64 + 128*64 + 128*64){
    int ii = i - 144*72 - 144*64 - 128*64; int t = ii/64, k2 = ii%64;
    WPlo[ii] = pack_h2(Wlo[(2*k2)*128+t]*is128, Wlo[(2*k2+1)*128+t]*is128);
  } else if (i < 144*72 + 144*64 + 128*64 + 128*64 + 4*64){
    int ii = i - 144*72 - 144*64 - 128*64 - 128*64; int t = ii/64, k2 = ii%64;
    WPso[ii] = pack_h2(Wso[(2*k2)*4+t]*is128, Wso[(2*k2+1)*4+t]*is128);
  }
}

// ---------------------------------------------------------------------------
// Node L1: X0L1 stored f16 (N x 64)
// ---------------------------------------------------------------------------
__global__ void k_node_l1(const int* __restrict__ xs, const float* __restrict__ emb,
                          const float* __restrict__ Wlin, const float* __restrict__ Wsc,
                          _Float16* __restrict__ X0, float* __restrict__ SC0){
  __shared__ float hs[4][64];
  int n0 = blockIdx.x*4;
  int t  = threadIdx.x;
  {
    int j = t>>6, k = t&63;
    hs[j][k] = emb[xs[n0+j]*64 + k];
  }
  __syncthreads();
  if (t < 64){
    float acc[4] = {};
    for (int k=0;k<64;k++){
      float wv = Wlin[k*64 + t];
      #pragma unroll
      for (int j=0;j<4;j++) acc[j] += hs[j][k]*wv;
    }
    #pragma unroll
    for (int j=0;j<4;j++) X0[(size_t)(n0+j)*64 + t] = (_Float16)(acc[j]*0.125f);
  } else if (t < 208){
    int o = t - 64;
    float acc[4] = {};
    for (int k=0;k<64;k++){
      float wv = Wsc[k*144 + o];
      #pragma unroll
      for (int j=0;j<4;j++) acc[j] += hs[j][k]*wv;
    }
    #pragma unroll
    for (int j=0;j<4;j++) SC0[(size_t)(n0+j)*144 + o] = acc[j]*0.125f;
  }
}

// ---------------------------------------------------------------------------
// Radial hidden for ALL edges: H[e][64] = silu(hb@W1/4), f16.
// ---------------------------------------------------------------------------
__global__ __launch_bounds__(256) void k_hidden(
    const float* __restrict__ EG, const float* __restrict__ W1,
    _Float16* __restrict__ H){
  __shared__ float w1s[16*64];
  int tid = threadIdx.x;
  for (int i=tid;i<16*64;i+=256) w1s[i] = W1[i]*0.25f;
  __syncthreads();
  int lane = tid & 63, wib = tid >> 6;
  int gw = blockIdx.x*4 + wib, nw = gridDim.x*4;
  for (int e = gw; e < N_EDGES; e += nw){
    const float* g8 = EG + (size_t)e*24 + 8;
    float a0 = 0.0f, a1 = 0.0f;
    #pragma unroll
    for (int b=0;b<8;b++){
      a0 = fmaf(g8[b],   w1s[b*64 + lane],     a0);
      a1 = fmaf(g8[8+b], w1s[(8+b)*64 + lane], a1);
    }
    H[(size_t)e*64 + lane] = (_Float16)siluf(a0 + a1);
  }
}

// ---------------------------------------------------------------------------
// Column scale folding
// ---------------------------------------------------------------------------
template<int MODE>
__device__ __forceinline__ float colscale(int c){
  if constexpr (MODE == 1){           // L2
    if (c >= 272 && c < 288) return 0.57735027f;   // m0b 1/sqrt(3)
    if (c >= 288 && c < 304) return 0.40824829f;   // m1c 1/sqrt(6)
    return 1.0f;
  } else if constexpr (MODE == 2){    // LO
    return (c >= 128) ? 0.57735027f : 1.0f;        // m0b 1/sqrt(3)
  }
  return 1.0f;                        // L1
}

// ---------------------------------------------------------------------------
// Pure MFMA GEMM over edge chunk, LINEAR column layout (coalesced store;
// layouts HW-verified R9/R10)
// ---------------------------------------------------------------------------
template<int NT, int MODE>
__global__ __launch_bounds__(256) void k_ww_mfma(
    int e0c, int e1c, const _Float16* __restrict__ H,
    const float* __restrict__ W2, _Float16* __restrict__ WW){
  constexpr int NCOL = NT*16;
  constexpr int NTW  = (NT + 3) / 4;      // col-tiles per wave
  int tid = threadIdx.x;
  int lane = tid & 63, wib = tid >> 6;
  int row = lane & 15, quad = lane >> 4;
  const float fold = 0.125f*0.28867513f;  // 1/8 * 1/sqrt(12)
  f16x8 B0[NTW], B1[NTW];
  #pragma unroll
  for (int t2=0; t2<NTW; t2++){
    int ct = wib*NTW + t2;
    int c  = ct*16 + row;
    bool valid = (ct < NT);
    float fs = valid ? fold*colscale<MODE>(c) : 0.0f;
    int ci = valid ? c : 0;
    #pragma unroll
    for (int j=0;j<8;j++){
      B0[t2][j] = (_Float16)(W2[(quad*8+j)*NCOL + ci]*fs);
      B1[t2][j] = (_Float16)(W2[(32+quad*8+j)*NCOL + ci]*fs);
    }
  }
  int ntiles = (e1c - e0c) >> 4;
  for (int t = blockIdx.x; t < ntiles; t += gridDim.x){
    int eb = e0c + t*16;
    const _Float16* hp = H + (size_t)(eb + row)*64 + quad*8;
    f16x8 A0 = *(const f16x8*)hp;
    f16x8 A1 = *(const f16x8*)(hp + 32);
    #pragma unroll
    for (int t2=0; t2<NTW; t2++){
      int ct = wib*NTW + t2;
      f32x4v d = __builtin_amdgcn_mfma_f32_16x16x32_f16(A0, B0[t2], (f32x4v){0.f,0.f,0.f,0.f}, 0,0,0);
      d = __builtin_amdgcn_mfma_f32_16x16x32_f16(A1, B1[t2], d, 0,0,0);
      if (ct < NT){
        int c0 = ct*16;
        #pragma unroll
        for (int j=0;j<4;j++){
          WW[(size_t)(eb - e0c + quad*4 + j)*NCOL + c0 + row] = (_Float16)d[j];
        }
      }
    }
  }
}

// ---------------------------------------------------------------------------
// L1 gather: linear WW, f16 X0 (src-prefetch)
// ---------------------------------------------------------------------------
__global__ __launch_bounds__(256) void k_gather_l1(
    const int* __restrict__ off, const int* __restrict__ srcs, const float* __restrict__ eg,
    const _Float16* __restrict__ WW, const _Float16* __restrict__ X0,
    float* __restrict__ A0, float* __restrict__ A1, int e0, int e1, int first){
  int tid = threadIdx.x, lane = tid & 63;
  int gw = (blockIdx.x*256 + tid) >> 6;
  int nw = (gridDim.x*256) >> 6;
  for (int n = gw; n < N_NODES; n += nw){
    int ib = off[n], ie = off[n+1];
    if (ib < e0) ib = e0;
    if (ie > e1) ie = e1;
    if (!first && ib >= ie) continue;
    float a0a = 0.0f, a1a[3] = {0,0,0};
    if (ib < ie){
      int src = srcs[ib];
      for (int i = ib; i < ie; i++){
        float x0 = (float)X0[(size_t)src*64 + lane];
        if (i+1 < ie) src = srcs[i+1];
        const float* g = eg + (size_t)i*24;
        const _Float16* w = WW + (size_t)(i - e0)*128;
        float w0  = (float)w[lane];
        float w1v = (float)w[64 + lane];
        float m0 = x0*w0, m1 = x0*w1v;
        a0a += m0;
        a1a[0] += m1*g[0]; a1a[1] += m1*g[1]; a1a[2] += m1*g[2];
      }
    }
    float* p = A1 + (size_t)n*192 + lane*3;
    if (first){
      A0[(size_t)n*64 + lane] = a0a;
      p[0] = a1a[0]; p[1] = a1a[1]; p[2] = a1a[2];
    } else {
      A0[(size_t)n*64 + lane] += a0a;
      p[0] += a1a[0]; p[1] += a1a[1]; p[2] += a1a[2];
    }
  }
}

// ---------------------------------------------------------------------------
// L2 gather: linear WW, paired X0, stride-4 X1, precomputed M for m1d
// ---------------------------------------------------------------------------
__global__ __launch_bounds__(256) void k_gather_l2(
    const int* __restrict__ off, const int* __restrict__ srcs, const float* __restrict__ eg,
    const _Float16* __restrict__ WW, const _Float16* __restrict__ X0, const _Float16* __restrict__ X1,
    float* __restrict__ A0, float* __restrict__ A1, int e0, int e1, int first){
  int tid = threadIdx.x, lane = tid & 63;
  int grp = lane >> 4, v = lane & 15;
  int gw = (blockIdx.x*256 + tid) >> 6;
  int nw = (gridDim.x*256) >> 6;
  for (int n = gw; n < N_NODES; n += nw){
    int ib = off[n], ie = off[n+1];
    if (ib < e0) ib = e0;
    if (ie > e1) ie = e1;
    if (!first && ib >= ie) continue;
    float a0a=0.f, a0b=0.f, a0c=0.f;
    float a1a[3]={0,0,0}, a1b[3]={0,0,0}, a1g[3]={0,0,0};
    if (ib < ie){
      int src = srcs[ib];
      for (int i = ib; i < ie; i++){
        float2 x0p = unpack_h2(((const unsigned*)(X0 + (size_t)src*128))[lane]);
        uint2 x1u = ((const uint2*)(X1 + (size_t)src*64))[v];
        float2 xab = unpack_h2(x1u.x);
        float2 xcp = unpack_h2(x1u.y);
        float xx = xab.x, xy = xab.y, xz = xcp.x;
        if (i+1 < ie) src = srcs[i+1];
        const float* g = eg + (size_t)i*24;
        const _Float16* w = WW + (size_t)(i - e0)*320;
        float w0  = (float)w[lane];
        float w1v = (float)w[ 64 + lane];
        float w2v = (float)w[128 + lane];
        float w3v = (float)w[192 + lane];
        float w4  = (float)w[256 + lane];
        float sx = g[0], sy = g[1], sz = g[2];
        a0a += x0p.x*w0;
        a0b += x0p.y*w1v;
        float ma = x0p.x*w2v, mb = x0p.y*w3v;
        a1a[0] += ma*sx; a1a[1] += ma*sy; a1a[2] += ma*sz;
        a1b[0] += mb*sx; a1b[1] += mb*sy; a1b[2] += mb*sz;
        if (grp == 0){
          a1g[0] += w4*xx; a1g[1] += w4*xy; a1g[2] += w4*xz;
        } else if (grp == 1){
          a0c += w4*(xx*sx + xy*sy + xz*sz);
        } else if (grp == 2){
          a1g[0] += w4*(xy*sz - xz*sy);
          a1g[1] += w4*(xz*sx - xx*sz);
          a1g[2] += w4*(xx*sy - xy*sx);
        } else {
          float M00=g[3], M01=g[4], M02=g[5], M12=g[6], M22=g[7];
          float M11 = -(M00 + M22);
          a1g[0] += w4*(xx*M00 + xy*M01 + xz*M02);
          a1g[1] += w4*(xx*M01 + xy*M11 + xz*M12);
          a1g[2] += w4*(xx*M02 + xy*M12 + xz*M22);
        }
      }
    }
    float* a0 = A0 + (size_t)n*144;
    float* a1 = A1 + (size_t)n*528;
    int gbase = (grp == 0) ? 128 : (grp == 2) ? 144 : (grp == 3) ? 160 : -1;
    if (first){
      a0[lane] = a0a;
      a0[64 + lane] = a0b;
      if (grp == 1) a0[128 + v] = a0c;
      float* p = a1 + lane*3;
      p[0] = a1a[0]; p[1] = a1a[1]; p[2] = a1a[2];
      p = a1 + (64 + lane)*3;
      p[0] = a1b[0]; p[1] = a1b[1]; p[2] = a1b[2];
      if (gbase >= 0){
        p = a1 + (gbase + v)*3;
        p[0] = a1g[0]; p[1] = a1g[1]; p[2] = a1g[2];
      }
    } else {
      a0[lane] += a0a;
      a0[64 + lane] += a0b;
      if (grp == 1) a0[128 + v] += a0c;
      float* p = a1 + lane*3;
      p[0] += a1a[0]; p[1] += a1a[1]; p[2] += a1a[2];
      p = a1 + (64 + lane)*3;
      p[0] += a1b[0]; p[1] += a1b[1]; p[2] += a1b[2];
      if (gbase >= 0){
        p = a1 + (gbase + v)*3;
        p[0] += a1g[0]; p[1] += a1g[1]; p[2] += a1g[2];
      }
    }
  }
}

// ---------------------------------------------------------------------------
// LO gather: linear WW, paired X0, stride-4 X1
// ---------------------------------------------------------------------------
__global__ __launch_bounds__(256) void k_gather_lo(
    const int* __restrict__ off, const int* __restrict__ srcs, const float* __restrict__ eg,
    const _Float16* __restrict__ WW, const _Float16* __restrict__ X0, const _Float16* __restrict__ X1,
    float* __restrict__ A0, int e0, int e1, int first){
  int tid = threadIdx.x, lane = tid & 63, v = lane & 15;
  int gw = (blockIdx.x*256 + tid) >> 6;
  int nw = (gridDim.x*256) >> 6;
  for (int n = gw; n < N_NODES; n += nw){
    int ib = off[n], ie = off[n+1];
    if (ib < e0) ib = e0;
    if (ie > e1) ie = e1;
    if (!first && ib >= ie) continue;
    float a0a = 0.f, a0b = 0.f, a0c = 0.f;
    if (ib < ie){
      int src = srcs[ib];
      for (int i = ib; i < ie; i++){
        float2 x0p = unpack_h2(((const unsigned*)(X0 + (size_t)src*128))[lane]);
        uint2 x1u = ((const uint2*)(X1 + (size_t)src*64))[v];
        float2 xab = unpack_h2(x1u.x);
        float2 xcp = unpack_h2(x1u.y);
        if (i+1 < ie) src = srcs[i+1];
        const float* g = eg + (size_t)i*24;
        const _Float16* w = WW + (size_t)(i - e0)*144;
        float w0  = (float)w[lane];
        float w1v = (float)w[64 + lane];
        float w2v = (float)w[128 + v];
        a0a += x0p.x*w0;
        a0b += x0p.y*w1v;
        float dot = xab.x*g[0] + xab.y*g[1] + xcp.x*g[2];
        a0c += w2v*dot;
      }
    }
    float* a0 = A0 + (size_t)n*144;
    if (first){
      a0[lane] = a0a;
      a0[64 + lane] = a0b;
      if (lane < 16) a0[128 + lane] = a0c;
    } else {
      a0[lane] += a0a;
      a0[64 + lane] += a0b;
      if (lane < 16) a0[128 + lane] += a0c;
    }
  }
}

// ---------------------------------------------------------------------------
// L1 update: f32 LDS-staged activations + W21 staged in LDS
// ---------------------------------------------------------------------------
__global__ __launch_bounds__(256) void k_upd_l1(
    const float* __restrict__ A0, const float* __restrict__ A1,
    const float* __restrict__ SC0,
    const float* __restrict__ W20, const float* __restrict__ W21,
    float* __restrict__ H0, float* __restrict__ H1){
  __shared__ float a0s[8*64];
  __shared__ float a1s[8*192];
  __shared__ float w21s[64*16];
  __shared__ float sig[8][16];
  __shared__ float g1s[8][48];
  int n0 = blockIdx.x*8, t = threadIdx.x;
  {
    const float4* s0 = (const float4*)(A0 + (size_t)n0*64);
    float4* d0 = (float4*)a0s;
    for (int i=t;i<8*64/4;i+=256) d0[i] = s0[i];
    const float4* s1 = (const float4*)(A1 + (size_t)n0*192);
    float4* d1 = (float4*)a1s;
    for (int i=t;i<8*192/4;i+=256) d1[i] = s1[i];
    const float4* sw = (const float4*)W21;
    float4* dw = (float4*)w21s;
    for (int i=t;i<64*16/4;i+=256) dw[i] = sw[i];
  }
  __syncthreads();
  if (t < 144){
    float acc[8] = {};
    for (int k=0;k<64;k++){
      float wv = W20[k*144 + t];
      #pragma unroll
      for (int j=0;j<8;j++) acc[j] += a0s[j*64 + k]*wv;
    }
    #pragma unroll
    for (int j=0;j<8;j++){
      float gg = acc[j]*0.125f + SC0[(size_t)(n0+j)*144 + t];
      if (t < 128) H0[(size_t)(n0+j)*128 + t] = siluf(gg);
      else         sig[j][t-128] = sigmf(gg);
    }
  } else if (t < 192){
    int idx = t-144, v = idx/3, k = idx%3;
    float acc[8] = {};
    for (int u=0;u<64;u++){
      float wv = w21s[u*16 + v];
      #pragma unroll
      for (int j=0;j<8;j++) acc[j] += a1s[j*192 + u*3 + k]*wv;
    }
    #pragma unroll
    for (int j=0;j<8;j++) g1s[j][idx] = acc[j]*0.125f;
  }
  __syncthreads();
  if (t >= 144 && t < 192){
    int idx = t-144, v = idx/3;
    #pragma unroll
    for (int j=0;j<8;j++) H1[(size_t)(n0+j)*48 + idx] = sig[j][v]*g1s[j][idx];
  }
}

// ---------------------------------------------------------------------------
// L2 node linears: f16 staging + packed weights; X0 paired, X1 stride-4
// ---------------------------------------------------------------------------
__global__ __launch_bounds__(384) void k_lin_l2(
    const float* __restrict__ H0, const float* __restrict__ H1,
    const unsigned* __restrict__ WPs, const float* __restrict__ Wsc1,
    const unsigned* __restrict__ WPl, const float* __restrict__ Wl1,
    float* __restrict__ SC0, float* __restrict__ SC1,
    _Float16* __restrict__ X0,  _Float16* __restrict__ X1){
  __shared__ uint4v h0h8[128];
  __shared__ float h1s[8*48];
  int n0 = blockIdx.x*8, t = threadIdx.x;
  if (t < 128){
    const float4* s0 = (const float4*)(H0 + (size_t)n0*128);
    float4 f0 = s0[t*2], f1 = s0[t*2+1];
    uint4v u;
    u.x = pack_h2(f0.x, f0.y); u.y = pack_h2(f0.z, f0.w);
    u.z = pack_h2(f1.x, f1.y); u.w = pack_h2(f1.z, f1.w);
    h0h8[t] = u;
  } else if (t < 224){
    int i = t - 128;
    const float4* s1 = (const float4*)(H1 + (size_t)n0*48);
    if (i < 96) ((float4*)h1s)[i] = s1[i];
  }
  __syncthreads();
  const uint4v* wps4 = (const uint4v*)WPs;
  const uint4v* wpl4 = (const uint4v*)WPl;
  if (t < 144){
    float acc[8] = {};
    for (int kq=0;kq<16;kq++){
      uint4v wq = wps4[t*16 + kq];
      #pragma unroll
      for (int j=0;j<8;j++){
        uint4v av = h0h8[j*16 + kq];
        acc[j] = dot8q(wq, av, acc[j]);
      }
    }
    #pragma unroll
    for (int j=0;j<8;j++) SC0[(size_t)(n0+j)*144 + t] = acc[j];
  } else if (t < 192){
    int idx = t-144, v = idx/3, k = idx%3;
    float acc[8] = {};
    for (int u=0;u<16;u++){
      float wv = Wsc1[u*16 + v];
      #pragma unroll
      for (int j=0;j<8;j++) acc[j] += h1s[j*48 + u*3 + k]*wv;
    }
    #pragma unroll
    for (int j=0;j<8;j++) SC1[(size_t)(n0+j)*48 + idx] = acc[j]*0.25f;
  } else if (t < 320){
    int o = t-192;
    float acc[8] = {};
    for (int kq=0;kq<16;kq++){
      uint4v wq = wpl4[o*16 + kq];
      #pragma unroll
      for (int j=0;j<8;j++){
        uint4v av = h0h8[j*16 + kq];
        acc[j] = dot8q(wq, av, acc[j]);
      }
    }
    #pragma unroll
    for (int j=0;j<8;j++) X0[(size_t)(n0+j)*128 + (o&63)*2 + (o>>6)] = (_Float16)acc[j];
  } else if (t < 368){
    int idx = t-320, v = idx/3, k = idx%3;
    float acc[8] = {};
    for (int u=0;u<16;u++){
      float wv = Wl1[u*16 + v];
      #pragma unroll
      for (int j=0;j<8;j++) acc[j] += h1s[j*48 + u*3 + k]*wv;
    }
    #pragma unroll
    for (int j=0;j<8;j++) X1[(size_t)(n0+j)*64 + v*4 + k] = (_Float16)(acc[j]*0.25f);
  }
}

// ---------------------------------------------------------------------------
// L2 update: f16 A0 staging + packed f16 W20 + dot2 (W21 from global, L2-hot)
// ---------------------------------------------------------------------------
__global__ __launch_bounds__(256) void k_upd_l2(
    const float* __restrict__ A0, const float* __restrict__ A1,
    const float* __restrict__ SC0, const float* __restrict__ SC1,
    const unsigned* __restrict__ WPu, const float* __restrict__ W21,
    float* __restrict__ H0, float* __restrict__ H1){
  __shared__ uint4v a0h8[144];
  __shared__ float a1s[8*528];
  __shared__ float sig[8][16];
  __shared__ float g1s[8][48];
  int n0 = blockIdx.x*8, t = threadIdx.x;
  if (t < 144){
    const float4* s0 = (const float4*)(A0 + (size_t)n0*144);
    float4 f0 = s0[t*2], f1 = s0[t*2+1];
    uint4v u;
    u.x = pack_h2(f0.x, f0.y); u.y = pack_h2(f0.z, f0.w);
    u.z = pack_h2(f1.x, f1.y); u.w = pack_h2(f1.z, f1.w);
    a0h8[t] = u;
  }
  {
    const float4* s1 = (const float4*)(A1 + (size_t)n0*528);
    float4* d1 = (float4*)a1s;
    for (int i=t;i<8*528/4;i+=256) d1[i] = s1[i];
  }
  __syncthreads();
  const uint4v* wpu4 = (const uint4v*)WPu;
  if (t < 144){
    float acc[8] = {};
    for (int kq=0;kq<18;kq++){
      uint4v wq = wpu4[t*18 + kq];
      #pragma unroll
      for (int j=0;j<8;j++){
        uint4v av = a0h8[j*18 + kq];
        acc[j] = dot8q(wq, av, acc[j]);
      }
    }
    #pragma unroll
    for (int j=0;j<8;j++){
      float gg = acc[j] + SC0[(size_t)(n0+j)*144 + t];
      if (t < 128) H0[(size_t)(n0+j)*128 + t] = siluf(gg);
      else         sig[j][t-128] = sigmf(gg);
    }
  } else if (t < 192){
    int idx = t-144, v = idx/3, k = idx%3;
    float acc[8] = {};
    for (int u=0;u<176;u++){
      float wv = W21[u*16 + v];
      #pragma unroll
      for (int j=0;j<8;j++) acc[j] += a1s[j*528 + u*3 + k]*wv;
    }
    #pragma unroll
    for (int j=0;j<8;j++) g1s[j][idx] = acc[j]*0.075377836f + SC1[(size_t)(n0+j)*48 + idx];
  }
  __syncthreads();
  if (t >= 144 && t < 192){
    int idx = t-144, v = idx/3;
    #pragma unroll
    for (int j=0;j<8;j++) H1[(size_t)(n0+j)*48 + idx] = sig[j][v]*g1s[j][idx];
  }
}

// ---------------------------------------------------------------------------
// LO node linears: f16 staging + packed weights; X0 paired, X1 stride-4
// ---------------------------------------------------------------------------
__global__ __launch_bounds__(256) void k_lin_lo(
    const float* __restrict__ H0, const float* __restrict__ H1,
    const unsigned* __restrict__ WPso,
    const unsigned* __restrict__ WPlo, const float* __restrict__ Wl1,
    float* __restrict__ SCO, _Float16* __restrict__ X0, _Float16* __restrict__ X1){
  __shared__ uint4v h0h8[128];
  __shared__ float h1s[8*48];
  int n0 = blockIdx.x*8, t = threadIdx.x;
  if (t < 128){
    const float4* s0 = (const float4*)(H0 + (size_t)n0*128);
    float4 f0 = s0[t*2], f1 = s0[t*2+1];
    uint4v u;
    u.x = pack_h2(f0.x, f0.y); u.y = pack_h2(f0.z, f0.w);
    u.z = pack_h2(f1.x, f1.y); u.w = pack_h2(f1.z, f1.w);
    h0h8[t] = u;
  } else if (t < 224){
    int i = t - 128;
    const float4* s1 = (const float4*)(H1 + (size_t)n0*48);
    if (i < 96) ((float4*)h1s)[i] = s1[i];
  }
  __syncthreads();
  const uint4v* wso4 = (const uint4v*)WPso;
  const uint4v* wlo4 = (const uint4v*)WPlo;
  if (t < 4){
    float acc[8] = {};
    for (int kq=0;kq<16;kq++){
      uint4v wq = wso4[t*16 + kq];
      #pragma unroll
      for (int j=0;j<8;j++){
        uint4v av = h0h8[j*16 + kq];
        acc[j] = dot8q(wq, av, acc[j]);
      }
    }
    #pragma unroll
    for (int j=0;j<8;j++) SCO[(size_t)(n0+j)*4 + t] = acc[j];
  } else if (t < 132){
    int o = t-4;
    float acc[8] = {};
    for (int kq=0;kq<16;kq++){
      uint4v wq = wlo4[o*16 + kq];
      #pragma unroll
      for (int j=0;j<8;j++){
        uint4v av = h0h8[j*16 + kq];
        acc[j] = dot8q(wq, av, acc[j]);
      }
    }
    #pragma unroll
    for (int j=0;j<8;j++) X0[(size_t)(n0+j)*128 + (o&63)*2 + (o>>6)] = (_Float16)acc[j];
  } else if (t < 180){
    int idx = t-132, v = idx/3, k = idx%3;
    float acc[8] = {};
    for (int u=0;u<16;u++){
      float wv = Wl1[u*16 + v];
      #pragma unroll
      for (int j=0;j<8;j++) acc[j] += h1s[j*48 + u*3 + k]*wv;
    }
    #pragma unroll
    for (int j=0;j<8;j++) X1[(size_t)(n0+j)*64 + v*4 + k] = (_Float16)(acc[j]*0.25f);
  }
}

// ---------------------------------------------------------------------------
// Final: out = A0@LO_lin2_0/12 + SCO, 32 nodes/block, 128 active lanes
// ---------------------------------------------------------------------------
__global__ __launch_bounds__(256) void k_final(
    const float* __restrict__ A0, const float* __restrict__ SCO,
    const float* __restrict__ W, float* __restrict__ out){
  __shared__ float a0s[32*144];
  int n0 = blockIdx.x*32, t = threadIdx.x;
  {
    const float4* s0 = (const float4*)(A0 + (size_t)n0*144);
    float4* d0 = (float4*)a0s;
    for (int i=t;i<32*144/4;i+=256) d0[i] = s0[i];
  }
  __syncthreads();
  if (t < 128){
    int j = t >> 2, c = t & 3;
    float acc = 0.0f;
    for (int k=0;k<144;k++) acc += a0s[j*144 + k]*W[k*4 + c];
    int i = (n0 + j)*4 + c;
    out[i] = acc*(1.0f/12.0f) + SCO[i];
  }
}

// ---------------------------------------------------------------------------
extern "C" void kernel_launch(void* const* d_in, const int* in_sizes, int n_in,
                              void* d_out, int out_size, void* d_ws, size_t ws_size,
                              hipStream_t stream) {
  const int*   x   = (const int*)  d_in[0];
  const int*   ei  = (const int*)  d_in[1];
  const float* ev  = (const float*)d_in[2];
  const float* emb = (const float*)d_in[3];
  const float* L1_lin1_0 = (const float*)d_in[4];
  const float* L1_W1     = (const float*)d_in[5];
  const float* L1_W2     = (const float*)d_in[6];
  const float* L1_lin2_0 = (const float*)d_in[7];
  const float* L1_lin2_1 = (const float*)d_in[8];
  const float* L1_sc_0   = (const float*)d_in[9];
  const float* L2_lin1_0 = (const float*)d_in[10];
  const float* L2_lin1_1 = (const float*)d_in[11];
  const float* L2_W1     = (const float*)d_in[12];
  const float* L2_W2     = (const float*)d_in[13];
  const float* L2_lin2_0 = (const float*)d_in[14];
  const float* L2_lin2_1 = (const float*)d_in[15];
  const float* L2_sc_0   = (const float*)d_in[16];
  const float* L2_sc_1   = (const float*)d_in[17];
  const float* LO_lin1_0 = (const float*)d_in[18];
  const float* LO_lin1_1 = (const float*)d_in[19];
  const float* LO_W1     = (const float*)d_in[20];
  const float* LO_W2     = (const float*)d_in[21];
  const float* LO_lin2_0 = (const float*)d_in[22];
  const float* LO_sc_0   = (const float*)d_in[23];
  float* out = (float*)d_out;

  int* cnt  = (int*)d_ws;                    // N
  int* off  = cnt  + N_NODES;                // N+1
  int* pos  = off  + N_NODES + 1;            // N
  int* perm = pos  + N_NODES;                // E
  int* srcs = perm + N_EDGES;                // E  (pad ints to 540004 for 16B alignment)
  float* EG  = (float*)(((char*)d_ws) + ((size_t)540004 * 4));   // E*24
  _Float16* X0 = (_Float16*)(EG + (size_t)N_EDGES*24);  // N*128 f16 (paired; L1 uses first N*64)
  _Float16* X1 = (_Float16*)(X0 + (size_t)N_NODES*128); // N*64 f16 (stride-4)
  float* SC0 = (float*)(X1 + (size_t)N_NODES*64);       // N*144
  float* SC1 = SC0 + (size_t)N_NODES*144;    // N*48
  float* A0  = SC1 + (size_t)N_NODES*48;     // N*144
  float* A1  = A0  + (size_t)N_NODES*144;    // N*528
  float* H0  = A1  + (size_t)N_NODES*528;    // N*128
  float* H1  = H0  + (size_t)N_NODES*128;    // N*48
  _Float16* HH = (_Float16*)(H1 + (size_t)N_NODES*48);  // E*64 f16
  unsigned* WPu  = (unsigned*)(HH + (size_t)N_EDGES*64); // 144*72
  unsigned* WPs  = WPu  + 144*72;                        // 144*64
  unsigned* WPl  = WPs  + 144*64;                        // 128*64
  unsigned* WPlo = WPl  + 128*64;                        // 128*64
  unsigned* WPso = WPlo + 128*64;                        // 4*64
  _Float16* WW = (_Float16*)(WPso + 4*64);               // dynamic

  size_t used = (size_t)((char*)WW - (char*)d_ws);
  size_t avail = (ws_size > used) ? (ws_size - used) : 0;
  auto chunk_for = [&](int ncol)->int{
    size_t ce = avail / ((size_t)ncol * sizeof(_Float16));
    if (ce >= (size_t)N_EDGES) return N_EDGES;
    int c = (int)ce & ~15;
    return c < 4096 ? 4096 : c;
  };

  // CSR build + weight packing
  hipMemsetAsync(cnt, 0, N_NODES*sizeof(int), stream);
  k_count  <<<(N_EDGES+255)/256, 256, 0, stream>>>(ei, cnt);
  k_scan   <<<1, 1024, 0, stream>>>(cnt, off, pos);
  k_scatter<<<(N_EDGES+255)/256, 256, 0, stream>>>(ei, pos, perm, srcs);
  k_geom   <<<(N_EDGES+255)/256, 256, 0, stream>>>(ev, perm, EG);
  k_packw  <<<142, 256, 0, stream>>>(L2_lin2_0, L2_sc_0, L2_lin1_0,
                                     LO_lin1_0, LO_sc_0,
                                     WPu, WPs, WPl, WPlo, WPso);

  // ---- L1 ----
  k_node_l1<<<N_NODES/4, 256, 0, stream>>>(x, emb, L1_lin1_0, L1_sc_0, X0, SC0);
  k_hidden<<<2048, 256, 0, stream>>>(EG, L1_W1, HH);
  {
    int chunk = chunk_for(128);
    for (int e0 = 0; e0 < N_EDGES; e0 += chunk){
      int e1 = (e0 + chunk < N_EDGES) ? e0 + chunk : N_EDGES;
      k_ww_mfma<8,0><<<2048, 256, 0, stream>>>(e0, e1, HH, L1_W2, WW);
      k_gather_l1<<<5000, 256, 0, stream>>>(off, srcs, EG, WW, X0, A0, A1, e0, e1, e0==0);
    }
  }
  k_upd_l1<<<N_NODES/8, 256, 0, stream>>>(A0, A1, SC0, L1_lin2_0, L1_lin2_1, H0, H1);

  // ---- L2 ----
  k_lin_l2<<<N_NODES/8, 384, 0, stream>>>(H0, H1, WPs, L2_sc_1, WPl, L2_lin1_1,
                                          SC0, SC1, X0, X1);
  k_hidden<<<2048, 256, 0, stream>>>(EG, L2_W1, HH);
  {
    int chunk = chunk_for(320);
    for (int e0 = 0; e0 < N_EDGES; e0 += chunk){
      int e1 = (e0 + chunk < N_EDGES) ? e0 + chunk : N_EDGES;
      k_ww_mfma<20,1><<<2048, 256, 0, stream>>>(e0, e1, HH, L2_W2, WW);
      k_gather_l2<<<5000, 256, 0, stream>>>(off, srcs, EG, WW, X0, X1, A0, A1, e0, e1, e0==0);
    }
  }
  k_upd_l2<<<N_NODES/8, 256, 0, stream>>>(A0, A1, SC0, SC1, WPu, L2_lin2_1, H0, H1);

  // ---- LO ----
  k_lin_lo<<<N_NODES/8, 256, 0, stream>>>(H0, H1, WPso, WPlo, LO_lin1_1, SC1, X0, X1);
  k_hidden<<<2048, 256, 0, stream>>>(EG, LO_W1, HH);
  {
    int chunk = chunk_for(144);
    for (int e0 = 0; e0 < N_EDGES; e0 += chunk){
      int e1 = (e0 + chunk < N_EDGES) ? e0 + chunk : N_EDGES;
      k_ww_mfma<9,2><<<2048, 256, 0, stream>>>(e0, e1, HH, LO_W2, WW);
      k_gather_lo<<<5000, 256, 0, stream>>>(off, srcs, EG, WW, X0, X1, A0, e0, e1, e0==0);
    }
  }
  k_final<<<N_NODES/32, 256, 0, stream>>>(A0, SC1, LO_lin2_0, out);
}